// Round 6
// baseline (3166.973 us; speedup 1.0000x reference)
//
#include <hip/hip_runtime.h>

#define B_    128
#define T_    1024
#define I_    64
#define H_    256
#define DEC_  128
#define C_    64
#define NWG   128          // 64 unit-slices x 2 sample halves
#define KTOT  320          // K = H (256) + I (64)
#define LDK   328          // padded LDS stride (ushorts), init staging only
#define STEPS (T_ + DEC_)
#define RING  32           // h-version ring slots
#define SAFE  24           // wave-barrier period (skew bound < RING-2)

typedef short bf16x8 __attribute__((ext_vector_type(8)));
typedef float f32x4  __attribute__((ext_vector_type(4)));
typedef unsigned u32x4 __attribute__((ext_vector_type(4)));

#define SCOPE_AGENT __HIP_MEMORY_SCOPE_AGENT

__device__ __forceinline__ f32x4 mf(bf16x8 a, bf16x8 b, f32x4 c) {
  return __builtin_amdgcn_mfma_f32_16x16x32_bf16(a, b, c, 0, 0, 0);
}

// coherence-point 16B ops (bypass per-XCD L2 via sc1); single-instruction = atomic snapshot
__device__ __forceinline__ u32x4 load16_coh(const void* p) {
  u32x4 r;
  asm volatile("global_load_dwordx4 %0, %1, off sc0 sc1" : "=v"(r) : "v"(p) : "memory");
  return r;
}
__device__ __forceinline__ void store16_coh(void* p, u32x4 v) {
  asm volatile("global_store_dwordx4 %0, %1, off sc0 sc1" :: "v"(p), "v"(v) : "memory");
}

// round-to-nearest-even split of f32 into bf16 hi + bf16 lo (v ~= hi + lo)
__device__ __forceinline__ void bf16_split(float v, unsigned short& hi, unsigned short& lo) {
  unsigned u = __float_as_uint(v);
  unsigned r = (u + 0x7fffu + ((u >> 16) & 1u)) & 0xffff0000u;
  hi = (unsigned short)(r >> 16);
  float fl = v - __uint_as_float(r);
  unsigned u2 = __float_as_uint(fl);
  unsigned r2 = (u2 + 0x7fffu + ((u2 >> 16) & 1u)) & 0xffff0000u;
  lo = (unsigned short)(r2 >> 16);
}

__device__ __forceinline__ float sigm(float v) { return 1.0f / (1.0f + __expf(-v)); }
__device__ __forceinline__ float tanh_(float v) {
  float e = __expf(-2.0f * fabsf(v));
  float t = (1.0f - e) / (1.0f + e);
  return (v >= 0.0f) ? t : -t;
}

// x (f32) -> bf16 hi/lo planes
__global__ __launch_bounds__(256) void xsplit_k(const float* __restrict__ x,
                                                unsigned short* __restrict__ xh,
                                                unsigned short* __restrict__ xl, int n4) {
  const int i = blockIdx.x * 256 + threadIdx.x;
  if (i >= n4) return;
  const float4 v = ((const float4*)x)[i];
  unsigned short h[4], l[4];
  bf16_split(v.x, h[0], l[0]);
  bf16_split(v.y, h[1], l[1]);
  bf16_split(v.z, h[2], l[2]);
  bf16_split(v.w, h[3], l[3]);
  uint2 uh, ul;
  uh.x = (unsigned)h[0] | ((unsigned)h[1] << 16);
  uh.y = (unsigned)h[2] | ((unsigned)h[3] << 16);
  ul.x = (unsigned)l[0] | ((unsigned)l[1] << 16);
  ul.y = (unsigned)l[2] | ((unsigned)l[3] << 16);
  ((uint2*)xh)[i] = uh;
  ((uint2*)xl)[i] = ul;
}

// Ring slot (128 KB): chunk(u, s) = 16 B at ((u*128 + s)*16):
//   bytes 0-7 hi bf16 of units u*4..u*4+3, bytes 8-15 lo (LSB of each lo word = gen tag bit).
// Version v of h lives in slot v%RING with gen (v>>5)&15 embedded in lo LSBs.
// Reader of version v polls its 16 chunks until gens match -> poll IS the data load.
// SINGLE-BIT tag check: skew < SAFE <= RING-2 and gen parity alternates per slot reuse,
// so bit0 of the z-dword alone discriminates (0xFF sentinel has bit0=1 vs gen-0's 0).
// PIPELINED DOUBLE-BUFFER POLL: two register arrays dA/dB alternate; while set X is
// checked, set Y's loads are already in flight; s_waitcnt vmcnt(16) waits only for the
// older set (vmcnt retires in issue order; any prologue ops older than the newest 16
// are also retired by the wait -> check is always valid). Detection granularity drops
// from a full MALL round-trip (~800 cy) to the issue+check interval.
// LIVENESS RULE (round-5 failure): on break the loser set has 16 in-flight loads whose
// register writes land LATER than the asm statement. Both sets' registers are therefore
// kept alive until an end-of-step s_waitcnt vmcnt(0) (asm with "+v" keep-alive
// constraints), placed AFTER the publish store so it is off the h->h critical path.
// Entry outstanding is 0 for every t>0 by construction.
// GATE-PER-LANE layout: weight rows ordered unit*4+gate, so each lane's f32x4 acc holds
// (i,f,g,o) for ONE unit -> lane-local LSTM cell; publish chunk assembled by 3 packed
// shfl_xor's. Ring/decb byte layout identical to the proven baseline.
__global__ __launch_bounds__(256, 1) void rnn5(
    const float* __restrict__ x,
    const unsigned short* __restrict__ x_hi,
    const unsigned short* __restrict__ x_lo,
    const int use_xs,
    const int* __restrict__ lengths,
    const float* __restrict__ W_ih, const float* __restrict__ W_hh,
    const float* __restrict__ b_ih, const float* __restrict__ b_hh,
    char* __restrict__ arrb,
    char* __restrict__ ring,
    char* __restrict__ decb)
{
  __shared__ unsigned short Whi[16][LDK];   // init staging only
  __shared__ unsigned short Wlo[16][LDK];

  const int tid  = threadIdx.x;
  const int g    = blockIdx.x;
  const int uo   = g >> 1;
  const int sh   = g & 1;
  const int j0   = uo * 4;
  const int wave = tid >> 6;
  const int lane = tid & 63;
  const int q4   = lane >> 4;
  const int n15  = lane & 15;
  const int s    = sh * 64 + wave * 16 + n15;

  // ---- init: stage split weights into LDS, then lift fragments into VGPRs ----
  // row = unit*4 + gate  (gate-per-lane layout: acc reg e = gate e for unit q4)
  for (int e = tid; e < 16 * KTOT; e += 256) {
    const int row = e / KTOT;
    const int k   = e - row * KTOT;
    const int grow = (row & 3) * H_ + j0 + (row >> 2);   // gate = row&3, unit = row>>2
    const float v = (k < H_) ? W_hh[grow * H_ + k] : W_ih[grow * I_ + (k - H_)];
    unsigned short h16, l16; bf16_split(v, h16, l16);
    Whi[row][k] = h16; Wlo[row][k] = l16;
  }
  __syncthreads();

  bf16x8 Ah[10], Al[10];                 // weight fragments, resident in VGPRs
  #pragma unroll
  for (int kh = 0; kh < 8; ++kh) {
    const int k0 = kh * 32 + q4 * 8;
    Ah[kh] = *(const bf16x8*)&Whi[n15][k0];
    Al[kh] = *(const bf16x8*)&Wlo[n15][k0];
  }
  #pragma unroll
  for (int kx = 0; kx < 2; ++kx) {
    const int k0 = H_ + kx * 32 + q4 * 8;
    Ah[8 + kx] = *(const bf16x8*)&Whi[n15][k0];
    Al[8 + kx] = *(const bf16x8*)&Wlo[n15][k0];
  }
  float bias4[4];
  #pragma unroll
  for (int e = 0; e < 4; ++e) {
    const int grow = e * H_ + j0 + q4;   // gate = e, unit = q4
    bias4[e] = b_ih[grow] + b_hh[grow];
  }

  const int len_s = lengths[s];

  // publish version 0 (zeros, gen 0) to slot 0 -- readers poll, no barrier needed
  if (tid < 64) {
    const int sz = sh * 64 + tid;
    u32x4 z; z.x = 0u; z.y = 0u; z.z = 0u; z.w = 0u;
    store16_coh(ring + (((size_t)uo * 128 + sz) << 4), z);
  }

  // x-part gate prefetch (independent of h); a0 seeded with bias
  auto xpart = [&](int t, f32x4& a0, f32x4& a1, f32x4& a2) {
    #pragma unroll
    for (int e = 0; e < 4; ++e) { a0[e] = bias4[e]; a1[e] = 0.f; a2[e] = 0.f; }
    if (t >= T_) return;
    #pragma unroll
    for (int kx = 0; kx < 2; ++kx) {
      bf16x8 bh, bl;
      if (use_xs) {
        const int xo = (s * T_ + t) * I_ + kx * 32 + q4 * 8;
        bh = *(const bf16x8*)(x_hi + xo);
        bl = *(const bf16x8*)(x_lo + xo);
      } else {
        const float* xp = x + ((size_t)s * T_ + t) * I_ + kx * 32 + q4 * 8;
        const float4 xa = *(const float4*)xp;
        const float4 xb = *(const float4*)(xp + 4);
        union { bf16x8 v; unsigned short u[8]; } bxh, bxl;
        float xv[8] = {xa.x, xa.y, xa.z, xa.w, xb.x, xb.y, xb.z, xb.w};
        #pragma unroll
        for (int e2 = 0; e2 < 8; ++e2) bf16_split(xv[e2], bxh.u[e2], bxl.u[e2]);
        bh = bxh.v; bl = bxl.v;
      }
      a0 = mf(Ah[8 + kx], bh, a0);
      a1 = mf(Ah[8 + kx], bl, a1);
      a2 = mf(Al[8 + kx], bh, a2);
    }
  };

  f32x4 xa0, xa1, xa2;
  xpart(0, xa0, xa1, xa2);

  float c_st = 0.f;      // cell state for (unit q4, sample s) -- lane-local
  float h_st = 0.f;

  for (int t = 0; t < STEPS; ++t) {
    const char* rslot = ring + (size_t)(t & (RING - 1)) * 131072;
    const unsigned ebx = (unsigned)((t >> 5) & 1u);   // gen parity

    u32x4 dA[16], dB[16];
    bool useA = true;
    {
      const char* sb = rslot + ((size_t)s << 4);
      const unsigned cb = (unsigned)(q4 << 1);

#define ISSUE_SET(S) { \
      S[0]  = load16_coh(sb + ((size_t)(cb + 0)  << 11)); \
      S[1]  = load16_coh(sb + ((size_t)(cb + 1)  << 11)); \
      S[2]  = load16_coh(sb + ((size_t)(cb + 8)  << 11)); \
      S[3]  = load16_coh(sb + ((size_t)(cb + 9)  << 11)); \
      S[4]  = load16_coh(sb + ((size_t)(cb + 16) << 11)); \
      S[5]  = load16_coh(sb + ((size_t)(cb + 17) << 11)); \
      S[6]  = load16_coh(sb + ((size_t)(cb + 24) << 11)); \
      S[7]  = load16_coh(sb + ((size_t)(cb + 25) << 11)); \
      S[8]  = load16_coh(sb + ((size_t)(cb + 32) << 11)); \
      S[9]  = load16_coh(sb + ((size_t)(cb + 33) << 11)); \
      S[10] = load16_coh(sb + ((size_t)(cb + 40) << 11)); \
      S[11] = load16_coh(sb + ((size_t)(cb + 41) << 11)); \
      S[12] = load16_coh(sb + ((size_t)(cb + 48) << 11)); \
      S[13] = load16_coh(sb + ((size_t)(cb + 49) << 11)); \
      S[14] = load16_coh(sb + ((size_t)(cb + 56) << 11)); \
      S[15] = load16_coh(sb + ((size_t)(cb + 57) << 11)); }

#define WAIT_SET(S) asm volatile("s_waitcnt vmcnt(16)" \
      : "+v"(S[0]),"+v"(S[1]),"+v"(S[2]),"+v"(S[3]),"+v"(S[4]),"+v"(S[5]),"+v"(S[6]),"+v"(S[7]), \
        "+v"(S[8]),"+v"(S[9]),"+v"(S[10]),"+v"(S[11]),"+v"(S[12]),"+v"(S[13]),"+v"(S[14]),"+v"(S[15]) \
      :: "memory")

#define TAGDIFF(S, DF) { DF = 0u; \
      DF |= (S[0].z  ^ ebx); DF |= (S[1].z  ^ ebx); DF |= (S[2].z  ^ ebx); DF |= (S[3].z  ^ ebx); \
      DF |= (S[4].z  ^ ebx); DF |= (S[5].z  ^ ebx); DF |= (S[6].z  ^ ebx); DF |= (S[7].z  ^ ebx); \
      DF |= (S[8].z  ^ ebx); DF |= (S[9].z  ^ ebx); DF |= (S[10].z ^ ebx); DF |= (S[11].z ^ ebx); \
      DF |= (S[12].z ^ ebx); DF |= (S[13].z ^ ebx); DF |= (S[14].z ^ ebx); DF |= (S[15].z ^ ebx); }

      // entry: vmcnt outstanding = 0 for t>0 (end-of-step drain); at t=0 the prologue
      // ops in flight are retired by the first vmcnt(16) (they are older than dB).
      ISSUE_SET(dA)
      for (;;) {
        unsigned df;
        ISSUE_SET(dB)
        WAIT_SET(dA);
        TAGDIFF(dA, df)
        if (__all((int)((df & 1u) == 0u))) { useA = true; break; }
        ISSUE_SET(dA)
        WAIT_SET(dB);
        TAGDIFF(dB, df)
        if (__all((int)((df & 1u) == 0u))) { useA = false; break; }
      }
#undef ISSUE_SET
#undef WAIT_SET
#undef TAGDIFF
    }

    // split dependent MFMA chains: a-chain (x-part seeded, KH 0-3), b-chain (KH 4-7)
    f32x4 a0 = xa0, a1 = xa1, a2 = xa2;
    f32x4 b0, b1, b2;
    #pragma unroll
    for (int e = 0; e < 4; ++e) { b0[e] = 0.f; b1[e] = 0.f; b2[e] = 0.f; }
#define MM_KH(i, ACC0, ACC1, ACC2, DA, DB) { \
    union { u32x4 q; bf16x8 v; } _h, _l; \
    _h.q.x = DA.x; _h.q.y = DA.y; _h.q.z = DB.x; _h.q.w = DB.y; \
    _l.q.x = DA.z; _l.q.y = DA.w; _l.q.z = DB.z; _l.q.w = DB.w; \
    ACC0 = mf(Ah[i], _h.v, ACC0); ACC1 = mf(Ah[i], _l.v, ACC1); ACC2 = mf(Al[i], _h.v, ACC2); }
#define MM_ALL(S) \
    MM_KH(0, a0, a1, a2, S[0],  S[1])  MM_KH(1, a0, a1, a2, S[2],  S[3]) \
    MM_KH(2, a0, a1, a2, S[4],  S[5])  MM_KH(3, a0, a1, a2, S[6],  S[7]) \
    MM_KH(4, b0, b1, b2, S[8],  S[9])  MM_KH(5, b0, b1, b2, S[10], S[11]) \
    MM_KH(6, b0, b1, b2, S[12], S[13]) MM_KH(7, b0, b1, b2, S[14], S[15])
    if (useA) { MM_ALL(dA) } else { MM_ALL(dB) }
#undef MM_ALL
#undef MM_KH

    // lane-local LSTM cell: acc element e = gate e (i,f,g,o) for unit q4, sample s
    const bool update = (t < T_) ? (t < len_s) : true;
    const unsigned gnxt = (unsigned)(((t + 1) >> 5) & 15);
    const float gi = (a0[0] + b0[0]) + (a1[0] + b1[0]) + (a2[0] + b2[0]);
    const float gf = (a0[1] + b0[1]) + (a1[1] + b1[1]) + (a2[1] + b2[1]);
    const float gg = (a0[2] + b0[2]) + (a1[2] + b1[2]) + (a2[2] + b2[2]);
    const float go = (a0[3] + b0[3]) + (a1[3] + b1[3]) + (a2[3] + b2[3]);
    const float cn = sigm(gf) * c_st + sigm(gi) * tanh_(gg);
    const float hn = sigm(go) * tanh_(cn);
    c_st = update ? cn : c_st;
    h_st = update ? hn : h_st;

    unsigned short hh, hl;
    bf16_split(h_st, hh, hl);
    hl = (unsigned short)((hl & 0xFFFEu) | ((gnxt >> q4) & 1u));  // embed gen bit
    const unsigned p  = (unsigned)hh | ((unsigned)hl << 16);
    const unsigned p1 = (unsigned)__shfl_xor((int)p, 16, 64);     // unit q4^1
    const unsigned p2 = (unsigned)__shfl_xor((int)p, 32, 64);     // unit q4^2
    const unsigned p3 = (unsigned)__shfl_xor((int)p1, 32, 64);    // unit q4^3

    // assemble 16B chunk (valid ordering on q4==0 lanes: p,p1,p2,p3 = units 0..3);
    // byte layout identical to baseline: [hi0..hi3][lo0..lo3]
    u32x4 vh16;
    vh16.x = (p  & 0xFFFFu) | (p1 << 16);
    vh16.y = (p2 & 0xFFFFu) | (p3 << 16);
    vh16.z = (p >> 16)      | (p1 & 0xFFFF0000u);
    vh16.w = (p2 >> 16)     | (p3 & 0xFFFF0000u);
    const size_t chunk_off = ((size_t)uo * 128 + s) << 4;
    if (q4 == 0)
      store16_coh(ring + (size_t)((t + 1) & (RING - 1)) * 131072 + chunk_off, vh16);

    // off-critical-path: decoder log (plain store) + next x-part prefetch
    if (t >= T_ && q4 == 0) {
      const int td = t - T_;
      *(u32x4*)(decb + ((((size_t)td * 64 + uo) * 128 + s) << 4)) = vh16;
    }
    xpart(t + 1, xa0, xa1, xa2);

    // END-OF-STEP DRAIN + KEEP-ALIVE (the round-5 fix): wait for ALL outstanding VMEM
    // (loser poll set, publish/decb stores, xpart loads) while pinning both poll sets'
    // registers so late-landing loads write into still-reserved VGPRs. dB's live range
    // spans the drain via the second (no-op) asm, so its registers also can't be
    // reallocated before the wait completes. Off the h->h critical path (after publish).
    asm volatile("s_waitcnt vmcnt(0)"
      : "+v"(dA[0]),"+v"(dA[1]),"+v"(dA[2]),"+v"(dA[3]),
        "+v"(dA[4]),"+v"(dA[5]),"+v"(dA[6]),"+v"(dA[7]),
        "+v"(dA[8]),"+v"(dA[9]),"+v"(dA[10]),"+v"(dA[11]),
        "+v"(dA[12]),"+v"(dA[13]),"+v"(dA[14]),"+v"(dA[15])
      :: "memory");
    asm volatile(""
      : "+v"(dB[0]),"+v"(dB[1]),"+v"(dB[2]),"+v"(dB[3]),
        "+v"(dB[4]),"+v"(dB[5]),"+v"(dB[6]),"+v"(dB[7]),
        "+v"(dB[8]),"+v"(dB[9]),"+v"(dB[10]),"+v"(dB[11]),
        "+v"(dB[12]),"+v"(dB[13]),"+v"(dB[14]),"+v"(dB[15]));

    // periodic wave-level barrier: bounds skew < SAFE so ring slots are never
    // overwritten while a lagging reader still needs them (SAFE <= RING-2)
    if ((t % SAFE) == (SAFE - 1)) {
      const unsigned ep = (unsigned)(t + 1);
      const int wid = g * 4 + wave;          // 0..511
      if (lane == 0)
        __hip_atomic_store((unsigned*)(arrb + (size_t)wid * 128), ep,
                           __ATOMIC_RELAXED, SCOPE_AGENT);
      bool okb;
      do {
        unsigned mn = ~0u;
        #pragma unroll
        for (int j = 0; j < 8; ++j) {
          unsigned v = __hip_atomic_load(
              (const unsigned*)(arrb + (size_t)(lane * 8 + j) * 128),
              __ATOMIC_RELAXED, SCOPE_AGENT);
          mn = (v < mn) ? v : mn;
        }
        okb = (mn >= ep);
      } while (!__all((int)okb));
    }
  }
}

// z[m][n] = relu(b1[n] + sum_k dec_h[m][k] * W1[n][k]),  m = td*128+s
__global__ __launch_bounds__(256) void mlp1(
    const char* __restrict__ decb,
    const float* __restrict__ W1, const float* __restrict__ b1,
    unsigned short* __restrict__ z_hi, unsigned short* __restrict__ z_lo)
{
  __shared__ unsigned short Ahi[32][264];
  __shared__ unsigned short Alo[32][264];
  __shared__ float bias_s[32];
  const int tid  = threadIdx.x;
  const int nblk = blockIdx.x & 7;
  const int mblk = blockIdx.x >> 3;     // = td
  const int n0   = nblk * 32;
  const int wave = tid >> 6, lane = tid & 63, q4 = lane >> 4, n15 = lane & 15;

  for (int e = tid; e < 32 * 256; e += 256) {
    const int row = e >> 8, k = e & 255;
    unsigned short h16, l16;
    bf16_split(W1[(n0 + row) * 256 + k], h16, l16);
    Ahi[row][k] = h16; Alo[row][k] = l16;
  }
  if (tid < 32) bias_s[tid] = b1[n0 + tid];
  __syncthreads();

  f32x4 acc[2][2];
  #pragma unroll
  for (int r = 0; r < 2; ++r)
    #pragma unroll
    for (int c = 0; c < 2; ++c)
      #pragma unroll
      for (int e = 0; e < 4; ++e) acc[r][c][e] = bias_s[16 * r + q4 * 4 + e];

  #pragma unroll
  for (int kh = 0; kh < 8; ++kh) {
    const int k0 = kh * 32 + q4 * 8;
    const bf16x8 ah0 = *(const bf16x8*)&Ahi[n15][k0];
    const bf16x8 ah1 = *(const bf16x8*)&Ahi[16 + n15][k0];
    const bf16x8 al0 = *(const bf16x8*)&Alo[n15][k0];
    const bf16x8 al1 = *(const bf16x8*)&Alo[16 + n15][k0];
    const int u0 = (kh * 4 + q4) * 2;
    #pragma unroll
    for (int c = 0; c < 2; ++c) {
      const int sloc = wave * 32 + c * 16 + n15;
      const char* base = decb + ((((size_t)mblk * 64 + u0) * 128 + sloc) << 4);
      const u32x4 A4 = *(const u32x4*)base;
      const u32x4 B4 = *(const u32x4*)(base + 2048);
      union { u32x4 q; bf16x8 v; } bh, bl;
      bh.q.x = A4.x; bh.q.y = A4.y; bh.q.z = B4.x; bh.q.w = B4.y;
      bl.q.x = A4.z; bl.q.y = A4.w; bl.q.z = B4.z; bl.q.w = B4.w;
      acc[0][c] = mf(ah0, bh.v, acc[0][c]);
      acc[1][c] = mf(ah1, bh.v, acc[1][c]);
      acc[0][c] = mf(ah0, bl.v, acc[0][c]);
      acc[1][c] = mf(ah1, bl.v, acc[1][c]);
      acc[0][c] = mf(al0, bh.v, acc[0][c]);
      acc[1][c] = mf(al1, bh.v, acc[1][c]);
    }
  }

  #pragma unroll
  for (int r = 0; r < 2; ++r)
    #pragma unroll
    for (int c = 0; c < 2; ++c) {
      const int sloc = wave * 32 + c * 16 + n15;
      const int m = mblk * 128 + sloc;
      const int ng = n0 + 16 * r + q4 * 4;
      unsigned short hh[4], ll[4];
      #pragma unroll
      for (int e = 0; e < 4; ++e) {
        const float v = fmaxf(acc[r][c][e], 0.0f);
        bf16_split(v, hh[e], ll[e]);
      }
      uint2 uh2, ul2;
      uh2.x = (unsigned)hh[0] | ((unsigned)hh[1] << 16);
      uh2.y = (unsigned)hh[2] | ((unsigned)hh[3] << 16);
      ul2.x = (unsigned)ll[0] | ((unsigned)ll[1] << 16);
      ul2.y = (unsigned)ll[2] | ((unsigned)ll[3] << 16);
      *(uint2*)(z_hi + m * 256 + ng) = uh2;
      *(uint2*)(z_lo + m * 256 + ng) = ul2;
    }
}

// out[s][td][c] = b2[c] + sum_n z[m][n] * W2[c][n],  m = td*128+s
__global__ __launch_bounds__(256) void mlp2(
    const unsigned short* __restrict__ z_hi, const unsigned short* __restrict__ z_lo,
    const float* __restrict__ W2, const float* __restrict__ b2,
    float* __restrict__ out)
{
  __shared__ unsigned short Ahi[32][264];
  __shared__ unsigned short Alo[32][264];
  __shared__ float bias_s[32];
  const int tid  = threadIdx.x;
  const int cblk = blockIdx.x & 1;
  const int mblk = blockIdx.x >> 1;
  const int c0   = cblk * 32;
  const int wave = tid >> 6, lane = tid & 63, q4 = lane >> 4, n15 = lane & 15;

  for (int e = tid; e < 32 * 256; e += 256) {
    const int row = e >> 8, k = e & 255;
    unsigned short h16, l16;
    bf16_split(W2[(c0 + row) * 256 + k], h16, l16);
    Ahi[row][k] = h16; Alo[row][k] = l16;
  }
  if (tid < 32) bias_s[tid] = b2[c0 + tid];
  __syncthreads();

  f32x4 acc[2][2];
  #pragma unroll
  for (int r = 0; r < 2; ++r)
    #pragma unroll
    for (int c = 0; c < 2; ++c)
      #pragma unroll
      for (int e = 0; e < 4; ++e) acc[r][c][e] = bias_s[16 * r + q4 * 4 + e];

  #pragma unroll
  for (int kh = 0; kh < 8; ++kh) {
    const int k0 = kh * 32 + q4 * 8;
    const bf16x8 ah0 = *(const bf16x8*)&Ahi[n15][k0];
    const bf16x8 ah1 = *(const bf16x8*)&Ahi[16 + n15][k0];
    const bf16x8 al0 = *(const bf16x8*)&Alo[n15][k0];
    const bf16x8 al1 = *(const bf16x8*)&Alo[16 + n15][k0];
    #pragma unroll
    for (int c = 0; c < 2; ++c) {
      const int m = mblk * 128 + wave * 32 + c * 16 + n15;
      const bf16x8 bh = *(const bf16x8*)(z_hi + m * 256 + k0);
      const bf16x8 bl = *(const bf16x8*)(z_lo + m * 256 + k0);
      acc[0][c] = mf(ah0, bh, acc[0][c]);
      acc[1][c] = mf(ah1, bh, acc[1][c]);
      acc[0][c] = mf(ah0, bl, acc[0][c]);
      acc[1][c] = mf(ah1, bl, acc[1][c]);
      acc[0][c] = mf(al0, bh, acc[0][c]);
      acc[1][c] = mf(al1, bh, acc[1][c]);
    }
  }

  #pragma unroll
  for (int r = 0; r < 2; ++r)
    #pragma unroll
    for (int c = 0; c < 2; ++c) {
      const int m  = mblk * 128 + wave * 32 + c * 16 + n15;
      const int ss = m & 127;
      const int td = m >> 7;
      const int cg = c0 + 16 * r + q4 * 4;
      *(f32x4*)(out + ss * (DEC_ * C_) + td * C_ + cg) = acc[r][c];
    }
}

extern "C" void kernel_launch(void* const* d_in, const int* in_sizes, int n_in,
                              void* d_out, int out_size, void* d_ws, size_t ws_size,
                              hipStream_t stream) {
  (void)in_sizes; (void)n_in; (void)out_size;
  const float* x    = (const float*)d_in[0];
  const int*   lens = (const int*)d_in[1];
  // d_in[2] = out_lengths (constant 128), unused
  const float* W_ih = (const float*)d_in[3];
  const float* W_hh = (const float*)d_in[4];
  const float* b_ih = (const float*)d_in[5];
  const float* b_hh = (const float*)d_in[6];
  const float* W1   = (const float*)d_in[7];
  const float* b1   = (const float*)d_in[8];
  const float* W2   = (const float*)d_in[9];
  const float* b2   = (const float*)d_in[10];
  float* out = (float*)d_out;

  char* ws8  = (char*)d_ws;
  char* arrb = ws8;                           // 64 KB wave-flag region (128 B per wave)
  char* ring = ws8 + 65536;                   // RING x 128 KB = 4 MB version ring
  char* decb = ws8 + 65536 + (size_t)RING * 131072;   // 16 MB decoder h log

  const size_t decb_end = 65536 + (size_t)RING * 131072 + 16777216ull;
  const size_t NEED_XS  = decb_end + 2ull * 16777216ull;   // + x hi/lo planes
  const int use_xs = (ws_size >= NEED_XS) ? 1 : 0;

  unsigned short* x_hi; unsigned short* x_lo;
  unsigned short* z_hi; unsigned short* z_lo;
  if (use_xs) {
    x_hi = (unsigned short*)(ws8 + decb_end);
    x_lo = x_hi + (size_t)B_ * T_ * I_;
    z_hi = (unsigned short*)(ws8 + decb_end);        // alias x_hi (dead after rnn5)
    z_lo = z_hi + (size_t)DEC_ * B_ * H_;
  } else {
    x_hi = nullptr; x_lo = nullptr;
    z_hi = (unsigned short*)(ws8 + decb_end);
    z_lo = z_hi + (size_t)DEC_ * B_ * H_;
  }

  (void)hipMemsetAsync(arrb, 0, 65536, stream);              // zero wave flags
  (void)hipMemsetAsync(ring, 0xFF, (size_t)RING * 131072, stream);  // gen-15 sentinel
  if (use_xs) {
    const int n4 = (B_ * T_ * I_) / 4;
    xsplit_k<<<(n4 + 255) / 256, 256, 0, stream>>>(x, x_hi, x_lo, n4);
  }
  rnn5<<<NWG, 256, 0, stream>>>(x, x_hi, x_lo, use_xs, lens,
                                W_ih, W_hh, b_ih, b_hh,
                                arrb, ring, decb);
  mlp1<<<1024, 256, 0, stream>>>(decb, W1, b1, z_hi, z_lo);
  mlp2<<<256, 256, 0, stream>>>(z_hi, z_lo, W2, b2, out);
}

// Round 9
// 3047.396 us; speedup vs baseline: 1.0392x; 1.0392x over previous
//
#include <hip/hip_runtime.h>

#define B_    128
#define T_    1024
#define I_    64
#define H_    256
#define DEC_  128
#define C_    64
#define NWG   128          // 64 unit-slices x 2 sample halves
#define KTOT  320          // K = H (256) + I (64)
#define LDK   328          // padded LDS stride (ushorts), init staging only
#define STEPS (T_ + DEC_)
#define RING  32           // h-version ring slots
#define SAFE  24           // wave-barrier period (skew bound < RING-2)

typedef short bf16x8 __attribute__((ext_vector_type(8)));
typedef float f32x4  __attribute__((ext_vector_type(4)));
typedef unsigned u32x4 __attribute__((ext_vector_type(4)));

#define SCOPE_AGENT __HIP_MEMORY_SCOPE_AGENT

__device__ __forceinline__ f32x4 mf(bf16x8 a, bf16x8 b, f32x4 c) {
  return __builtin_amdgcn_mfma_f32_16x16x32_bf16(a, b, c, 0, 0, 0);
}

// coherence-point 16B ops (bypass per-XCD L2 via sc1); single-instruction = atomic snapshot
__device__ __forceinline__ u32x4 load16_coh(const void* p) {
  u32x4 r;
  asm volatile("global_load_dwordx4 %0, %1, off sc0 sc1" : "=v"(r) : "v"(p) : "memory");
  return r;
}
__device__ __forceinline__ void store16_coh(void* p, u32x4 v) {
  asm volatile("global_store_dwordx4 %0, %1, off sc0 sc1" :: "v"(p), "v"(v) : "memory");
}

// round-to-nearest-even split of f32 into bf16 hi + bf16 lo (v ~= hi + lo)
__device__ __forceinline__ void bf16_split(float v, unsigned short& hi, unsigned short& lo) {
  unsigned u = __float_as_uint(v);
  unsigned r = (u + 0x7fffu + ((u >> 16) & 1u)) & 0xffff0000u;
  hi = (unsigned short)(r >> 16);
  float fl = v - __uint_as_float(r);
  unsigned u2 = __float_as_uint(fl);
  unsigned r2 = (u2 + 0x7fffu + ((u2 >> 16) & 1u)) & 0xffff0000u;
  lo = (unsigned short)(r2 >> 16);
}

__device__ __forceinline__ float sigm(float v) { return 1.0f / (1.0f + __expf(-v)); }
__device__ __forceinline__ float tanh_(float v) {
  float e = __expf(-2.0f * fabsf(v));
  float t = (1.0f - e) / (1.0f + e);
  return (v >= 0.0f) ? t : -t;
}

// x (f32) -> bf16 hi/lo planes
__global__ __launch_bounds__(256) void xsplit_k(const float* __restrict__ x,
                                                unsigned short* __restrict__ xh,
                                                unsigned short* __restrict__ xl, int n4) {
  const int i = blockIdx.x * 256 + threadIdx.x;
  if (i >= n4) return;
  const float4 v = ((const float4*)x)[i];
  unsigned short h[4], l[4];
  bf16_split(v.x, h[0], l[0]);
  bf16_split(v.y, h[1], l[1]);
  bf16_split(v.z, h[2], l[2]);
  bf16_split(v.w, h[3], l[3]);
  uint2 uh, ul;
  uh.x = (unsigned)h[0] | ((unsigned)h[1] << 16);
  uh.y = (unsigned)h[2] | ((unsigned)h[3] << 16);
  ul.x = (unsigned)l[0] | ((unsigned)l[1] << 16);
  ul.y = (unsigned)l[2] | ((unsigned)l[3] << 16);
  ((uint2*)xh)[i] = uh;
  ((uint2*)xl)[i] = ul;
}

// Ring slot (128 KB): chunk(u, s) = 16 B at ((u*128 + s)*16): s = VIRTUAL (length-sorted)
//   sample slot. bytes 0-7 hi bf16 of units u*4..u*4+3, bytes 8-15 lo (LSB = gen tag bit).
// Version v of h lives in slot v%RING with gen parity ((v>>5)&1) embedded in lo LSBs.
// Reader of version v polls its 16 chunks until gens match -> poll IS the data load.
// SINGLE-BIT tag check requires the freshness invariant: EVERY version of every chunk is
// written, so slot content differs from the wanted version by exactly one gen step
// (skew < SAFE <= RING-2). Round-7 failure: frozen groups stopped publishing ->
// multi-gen-stale slots false-matched parity at the decoder.
// LENGTH-SORTED GROUP FREEZING (traffic fix) + VALUE-REPUBLISH (correctness fix):
// samples are rank-sorted by length (descending) into virtual slots, so each 16-sample
// wave-group freezes as a unit at t >= gmax. Frozen waves skip poll+MFMA+cell+xpart
// (the latency chain and ~97% of their fabric traffic) but STILL publish their frozen
// h every step with the correct gen bit -- preserving the freshness invariant exactly.
// Consumers of a group's chunks are exactly that group's waves (across unit-WGs), which
// freeze together -> no reader ever waits on a frozen wave's ring data mid-freeze.
// Decoder path is the plain pv=t path. decb written at PHYSICAL s (mlp1/2 unchanged).
// Barrier keeps the PROVEN wave-uniform __all exit (divergent-exit spin was the round-8
// container-death suspect); frozen waves damp the spin with a wave-uniform s_sleep.
__global__ __launch_bounds__(256, 1) void rnn5(
    const float* __restrict__ x,
    const unsigned short* __restrict__ x_hi,
    const unsigned short* __restrict__ x_lo,
    const int use_xs,
    const int* __restrict__ lengths,
    const float* __restrict__ W_ih, const float* __restrict__ W_hh,
    const float* __restrict__ b_ih, const float* __restrict__ b_hh,
    char* __restrict__ arrb,
    char* __restrict__ ring,
    char* __restrict__ decb)
{
  __shared__ unsigned short Whi[16][LDK];   // init staging only
  __shared__ unsigned short Wlo[16][LDK];
  __shared__ int len_sh[128];
  __shared__ int perm_s[128];

  const int tid  = threadIdx.x;
  const int g    = blockIdx.x;
  const int uo   = g >> 1;
  const int sh   = g & 1;
  const int j0   = uo * 4;
  const int wave = tid >> 6;
  const int lane = tid & 63;
  const int q4   = lane >> 4;
  const int n15  = lane & 15;
  const int s    = sh * 64 + wave * 16 + n15;   // VIRTUAL sample slot (rank)

  // ---- init: length sort (identical in every WG; rank with index tie-break) ----
  if (tid < 128) len_sh[tid] = lengths[tid];
  __syncthreads();
  if (tid < 128) {
    const int li = len_sh[tid];
    int rank = 0;
    for (int j = 0; j < 128; ++j) {
      const int lj = len_sh[j];
      rank += (int)((lj > li) || (lj == li && j < tid));
    }
    perm_s[rank] = tid;
  }

  // ---- init: stage split weights into LDS, then lift fragments into VGPRs ----
  // row = unit*4 + gate  (gate-per-lane layout: acc reg e = gate e for unit q4)
  for (int e = tid; e < 16 * KTOT; e += 256) {
    const int row = e / KTOT;
    const int k   = e - row * KTOT;
    const int grow = (row & 3) * H_ + j0 + (row >> 2);   // gate = row&3, unit = row>>2
    const float v = (k < H_) ? W_hh[grow * H_ + k] : W_ih[grow * I_ + (k - H_)];
    unsigned short h16, l16; bf16_split(v, h16, l16);
    Whi[row][k] = h16; Wlo[row][k] = l16;
  }
  __syncthreads();

  const int s_phys = perm_s[s];               // physical sample for slot s
  const int len_s  = len_sh[s_phys];
  const int gmax   = len_sh[perm_s[sh * 64 + wave * 16]];  // group max (first = longest)

  bf16x8 Ah[10], Al[10];                 // weight fragments, resident in VGPRs
  #pragma unroll
  for (int kh = 0; kh < 8; ++kh) {
    const int k0 = kh * 32 + q4 * 8;
    Ah[kh] = *(const bf16x8*)&Whi[n15][k0];
    Al[kh] = *(const bf16x8*)&Wlo[n15][k0];
  }
  #pragma unroll
  for (int kx = 0; kx < 2; ++kx) {
    const int k0 = H_ + kx * 32 + q4 * 8;
    Ah[8 + kx] = *(const bf16x8*)&Whi[n15][k0];
    Al[8 + kx] = *(const bf16x8*)&Wlo[n15][k0];
  }
  float bias4[4];
  #pragma unroll
  for (int e = 0; e < 4; ++e) {
    const int grow = e * H_ + j0 + q4;   // gate = e, unit = q4
    bias4[e] = b_ih[grow] + b_hh[grow];
  }

  // publish version 0 (zeros, gen 0) to slot 0 -- readers poll, no barrier needed
  if (tid < 64) {
    const int sz = sh * 64 + tid;
    u32x4 z; z.x = 0u; z.y = 0u; z.z = 0u; z.w = 0u;
    store16_coh(ring + (((size_t)uo * 128 + sz) << 4), z);
  }

  // x-part gate prefetch (independent of h); a0 seeded with bias; x indexed by s_phys
  auto xpart = [&](int t, f32x4& a0, f32x4& a1, f32x4& a2) {
    #pragma unroll
    for (int e = 0; e < 4; ++e) { a0[e] = bias4[e]; a1[e] = 0.f; a2[e] = 0.f; }
    if (t >= T_) return;
    #pragma unroll
    for (int kx = 0; kx < 2; ++kx) {
      bf16x8 bh, bl;
      if (use_xs) {
        const int xo = (s_phys * T_ + t) * I_ + kx * 32 + q4 * 8;
        bh = *(const bf16x8*)(x_hi + xo);
        bl = *(const bf16x8*)(x_lo + xo);
      } else {
        const float* xp = x + ((size_t)s_phys * T_ + t) * I_ + kx * 32 + q4 * 8;
        const float4 xa = *(const float4*)xp;
        const float4 xb = *(const float4*)(xp + 4);
        union { bf16x8 v; unsigned short u[8]; } bxh, bxl;
        float xv[8] = {xa.x, xa.y, xa.z, xa.w, xb.x, xb.y, xb.z, xb.w};
        #pragma unroll
        for (int e2 = 0; e2 < 8; ++e2) bf16_split(xv[e2], bxh.u[e2], bxl.u[e2]);
        bh = bxh.v; bl = bxl.v;
      }
      a0 = mf(Ah[8 + kx], bh, a0);
      a1 = mf(Ah[8 + kx], bl, a1);
      a2 = mf(Al[8 + kx], bh, a2);
    }
  };

  f32x4 xa0, xa1, xa2;
  xpart(0, xa0, xa1, xa2);

  float c_st = 0.f;      // cell state for (unit q4, sample s) -- lane-local
  float h_st = 0.f;

  for (int t = 0; t < STEPS; ++t) {
    // group-freeze gate (wave-uniform): encoder active while t < gmax; decoder always.
    const bool active = (t < gmax) || (t >= T_);

    if (active) {
      if (t == T_) xpart(T_, xa0, xa1, xa2);   // reset xa to bias after frozen gap
      const char* rslot = ring + (size_t)(t & (RING - 1)) * 131072;
      const unsigned eb = (unsigned)((t >> 5) & 1u);   // gen parity

      // poll-load: re-issue all 16 chunks until every bit0 tag matches (poll IS the read)
      u32x4 d0,d1,d2,d3,d4,d5,d6,d7,d8,d9,d10,d11,d12,d13,d14,d15;
      for (;;) {
#define LD_KH(i, DA, DB) { \
        const char* _b = rslot + (((size_t)(((i) * 8 + (q4 << 1)) * 128 + s)) << 4); \
        DA = load16_coh(_b); DB = load16_coh(_b + 2048); }
        LD_KH(0, d0,  d1)  LD_KH(1, d2,  d3)  LD_KH(2, d4,  d5)  LD_KH(3, d6,  d7)
        LD_KH(4, d8,  d9)  LD_KH(5, d10, d11) LD_KH(6, d12, d13) LD_KH(7, d14, d15)
#undef LD_KH
        asm volatile("s_waitcnt vmcnt(0)"
          : "+v"(d0),"+v"(d1),"+v"(d2),"+v"(d3),"+v"(d4),"+v"(d5),"+v"(d6),"+v"(d7),
            "+v"(d8),"+v"(d9),"+v"(d10),"+v"(d11),"+v"(d12),"+v"(d13),"+v"(d14),"+v"(d15)
          :: "memory");
        unsigned ok = 1u;
#define CK(D) ok &= (unsigned)((D.z & 1u) == eb);
        CK(d0) CK(d1) CK(d2) CK(d3) CK(d4) CK(d5) CK(d6) CK(d7)
        CK(d8) CK(d9) CK(d10) CK(d11) CK(d12) CK(d13) CK(d14) CK(d15)
#undef CK
        if (__all((int)ok)) break;
      }

      // split dependent MFMA chains: a-chain (x-part seeded, KH 0-3), b-chain (KH 4-7)
      f32x4 a0 = xa0, a1 = xa1, a2 = xa2;
      f32x4 b0, b1, b2;
      #pragma unroll
      for (int e = 0; e < 4; ++e) { b0[e] = 0.f; b1[e] = 0.f; b2[e] = 0.f; }
#define MM_KH(i, ACC0, ACC1, ACC2, DA, DB) { \
      union { u32x4 q; bf16x8 v; } _h, _l; \
      _h.q.x = DA.x; _h.q.y = DA.y; _h.q.z = DB.x; _h.q.w = DB.y; \
      _l.q.x = DA.z; _l.q.y = DA.w; _l.q.z = DB.z; _l.q.w = DB.w; \
      ACC0 = mf(Ah[i], _h.v, ACC0); ACC1 = mf(Ah[i], _l.v, ACC1); ACC2 = mf(Al[i], _h.v, ACC2); }
      MM_KH(0, a0, a1, a2, d0,  d1)  MM_KH(1, a0, a1, a2, d2,  d3)
      MM_KH(2, a0, a1, a2, d4,  d5)  MM_KH(3, a0, a1, a2, d6,  d7)
      MM_KH(4, b0, b1, b2, d8,  d9)  MM_KH(5, b0, b1, b2, d10, d11)
      MM_KH(6, b0, b1, b2, d12, d13) MM_KH(7, b0, b1, b2, d14, d15)
#undef MM_KH

      // lane-local LSTM cell: acc element e = gate e (i,f,g,o) for unit q4, sample s
      const bool update = (t < T_) ? (t < len_s) : true;
      const float gi = (a0[0] + b0[0]) + (a1[0] + b1[0]) + (a2[0] + b2[0]);
      const float gf = (a0[1] + b0[1]) + (a1[1] + b1[1]) + (a2[1] + b2[1]);
      const float gg = (a0[2] + b0[2]) + (a1[2] + b1[2]) + (a2[2] + b2[2]);
      const float go = (a0[3] + b0[3]) + (a1[3] + b1[3]) + (a2[3] + b2[3]);
      const float cn = sigm(gf) * c_st + sigm(gi) * tanh_(gg);
      const float hn = sigm(go) * tanh_(cn);
      c_st = update ? cn : c_st;
      h_st = update ? hn : h_st;
    }

    // COMMON publish (active AND frozen): h_st value with gen bit for version t+1.
    // Frozen waves republish their frozen h -- every ring version stays written, so the
    // single-bit parity invariant holds globally (the round-7 fix).
    const unsigned gnxt = (unsigned)(((t + 1) >> 5) & 15);
    unsigned short hh, hl;
    bf16_split(h_st, hh, hl);
    hl = (unsigned short)((hl & 0xFFFEu) | ((gnxt >> q4) & 1u));  // embed gen bit
    const unsigned p  = (unsigned)hh | ((unsigned)hl << 16);
    const unsigned p1 = (unsigned)__shfl_xor((int)p, 16, 64);     // unit q4^1
    const unsigned p2 = (unsigned)__shfl_xor((int)p, 32, 64);     // unit q4^2
    const unsigned p3 = (unsigned)__shfl_xor((int)p, 48, 64);     // unit q4^3 (1-deep)

    // assemble 16B chunk (valid ordering on q4==0 lanes: p,p1,p2,p3 = units 0..3);
    // byte layout identical to baseline: [hi0..hi3][lo0..lo3]
    u32x4 vh16;
    vh16.x = (p  & 0xFFFFu) | (p1 << 16);
    vh16.y = (p2 & 0xFFFFu) | (p3 << 16);
    vh16.z = (p >> 16)      | (p1 & 0xFFFF0000u);
    vh16.w = (p2 >> 16)     | (p3 & 0xFFFF0000u);
    const size_t chunk_off = ((size_t)uo * 128 + s) << 4;
    if (q4 == 0)
      store16_coh(ring + (size_t)((t + 1) & (RING - 1)) * 131072 + chunk_off, vh16);

    if (active) {
      // off-critical-path: decoder log (plain store, PHYSICAL s) + next x-part prefetch
      if (t >= T_ && q4 == 0) {
        const int td = t - T_;
        *(u32x4*)(decb + ((((size_t)td * 64 + uo) * 128 + s_phys) << 4)) = vh16;
      }
      xpart(t + 1, xa0, xa1, xa2);
    }

    // periodic wave-level barrier: bounds skew < SAFE so ring slots are never
    // overwritten while a lagging reader still needs them (SAFE <= RING-2).
    // PROVEN __all exit (wave-uniform); frozen waves damp with wave-uniform s_sleep.
    if ((t % SAFE) == (SAFE - 1)) {
      asm volatile("s_waitcnt vmcnt(0)" ::: "memory");
      const unsigned ep = (unsigned)(t + 1);
      const int wid = g * 4 + wave;          // 0..511
      if (lane == 0)
        __hip_atomic_store((unsigned*)(arrb + (size_t)wid * 128), ep,
                           __ATOMIC_RELAXED, SCOPE_AGENT);
      bool okb;
      do {
        unsigned mn = ~0u;
        #pragma unroll
        for (int j = 0; j < 8; ++j) {
          unsigned v = __hip_atomic_load(
              (const unsigned*)(arrb + (size_t)(lane * 8 + j) * 128),
              __ATOMIC_RELAXED, SCOPE_AGENT);
          mn = (v < mn) ? v : mn;
        }
        okb = __all((int)(mn >= ep));
        if (!okb && !active) __builtin_amdgcn_s_sleep(32);
      } while (!okb);
    }
  }
}

// z[m][n] = relu(b1[n] + sum_k dec_h[m][k] * W1[n][k]),  m = td*128+s
__global__ __launch_bounds__(256) void mlp1(
    const char* __restrict__ decb,
    const float* __restrict__ W1, const float* __restrict__ b1,
    unsigned short* __restrict__ z_hi, unsigned short* __restrict__ z_lo)
{
  __shared__ unsigned short Ahi[32][264];
  __shared__ unsigned short Alo[32][264];
  __shared__ float bias_s[32];
  const int tid  = threadIdx.x;
  const int nblk = blockIdx.x & 7;
  const int mblk = blockIdx.x >> 3;     // = td
  const int n0   = nblk * 32;
  const int wave = tid >> 6, lane = tid & 63, q4 = lane >> 4, n15 = lane & 15;

  for (int e = tid; e < 32 * 256; e += 256) {
    const int row = e >> 8, k = e & 255;
    unsigned short h16, l16;
    bf16_split(W1[(n0 + row) * 256 + k], h16, l16);
    Ahi[row][k] = h16; Alo[row][k] = l16;
  }
  if (tid < 32) bias_s[tid] = b1[n0 + tid];
  __syncthreads();

  f32x4 acc[2][2];
  #pragma unroll
  for (int r = 0; r < 2; ++r)
    #pragma unroll
    for (int c = 0; c < 2; ++c)
      #pragma unroll
      for (int e = 0; e < 4; ++e) acc[r][c][e] = bias_s[16 * r + q4 * 4 + e];

  #pragma unroll
  for (int kh = 0; kh < 8; ++kh) {
    const int k0 = kh * 32 + q4 * 8;
    const bf16x8 ah0 = *(const bf16x8*)&Ahi[n15][k0];
    const bf16x8 ah1 = *(const bf16x8*)&Ahi[16 + n15][k0];
    const bf16x8 al0 = *(const bf16x8*)&Alo[n15][k0];
    const bf16x8 al1 = *(const bf16x8*)&Alo[16 + n15][k0];
    const int u0 = (kh * 4 + q4) * 2;
    #pragma unroll
    for (int c = 0; c < 2; ++c) {
      const int sloc = wave * 32 + c * 16 + n15;
      const char* base = decb + ((((size_t)mblk * 64 + u0) * 128 + sloc) << 4);
      const u32x4 A4 = *(const u32x4*)base;
      const u32x4 B4 = *(const u32x4*)(base + 2048);
      union { u32x4 q; bf16x8 v; } bh, bl;
      bh.q.x = A4.x; bh.q.y = A4.y; bh.q.z = B4.x; bh.q.w = B4.y;
      bl.q.x = A4.z; bl.q.y = A4.w; bl.q.z = B4.z; bl.q.w = B4.w;
      acc[0][c] = mf(ah0, bh.v, acc[0][c]);
      acc[1][c] = mf(ah1, bh.v, acc[1][c]);
      acc[0][c] = mf(ah0, bl.v, acc[0][c]);
      acc[1][c] = mf(ah1, bl.v, acc[1][c]);
      acc[0][c] = mf(al0, bh.v, acc[0][c]);
      acc[1][c] = mf(al1, bh.v, acc[1][c]);
    }
  }

  #pragma unroll
  for (int r = 0; r < 2; ++r)
    #pragma unroll
    for (int c = 0; c < 2; ++c) {
      const int sloc = wave * 32 + c * 16 + n15;
      const int m = mblk * 128 + sloc;
      const int ng = n0 + 16 * r + q4 * 4;
      unsigned short hh[4], ll[4];
      #pragma unroll
      for (int e = 0; e < 4; ++e) {
        const float v = fmaxf(acc[r][c][e], 0.0f);
        bf16_split(v, hh[e], ll[e]);
      }
      uint2 uh2, ul2;
      uh2.x = (unsigned)hh[0] | ((unsigned)hh[1] << 16);
      uh2.y = (unsigned)hh[2] | ((unsigned)hh[3] << 16);
      ul2.x = (unsigned)ll[0] | ((unsigned)ll[1] << 16);
      ul2.y = (unsigned)ll[2] | ((unsigned)ll[3] << 16);
      *(uint2*)(z_hi + m * 256 + ng) = uh2;
      *(uint2*)(z_lo + m * 256 + ng) = ul2;
    }
}

// out[s][td][c] = b2[c] + sum_n z[m][n] * W2[c][n],  m = td*128+s
__global__ __launch_bounds__(256) void mlp2(
    const unsigned short* __restrict__ z_hi, const unsigned short* __restrict__ z_lo,
    const float* __restrict__ W2, const float* __restrict__ b2,
    float* __restrict__ out)
{
  __shared__ unsigned short Ahi[32][264];
  __shared__ unsigned short Alo[32][264];
  __shared__ float bias_s[32];
  const int tid  = threadIdx.x;
  const int cblk = blockIdx.x & 1;
  const int mblk = blockIdx.x >> 1;
  const int c0   = cblk * 32;
  const int wave = tid >> 6, lane = tid & 63, q4 = lane >> 4, n15 = lane & 15;

  for (int e = tid; e < 32 * 256; e += 256) {
    const int row = e >> 8, k = e & 255;
    unsigned short h16, l16;
    bf16_split(W2[(c0 + row) * 256 + k], h16, l16);
    Ahi[row][k] = h16; Alo[row][k] = l16;
  }
  if (tid < 32) bias_s[tid] = b2[c0 + tid];
  __syncthreads();

  f32x4 acc[2][2];
  #pragma unroll
  for (int r = 0; r < 2; ++r)
    #pragma unroll
    for (int c = 0; c < 2; ++c)
      #pragma unroll
      for (int e = 0; e < 4; ++e) acc[r][c][e] = bias_s[16 * r + q4 * 4 + e];

  #pragma unroll
  for (int kh = 0; kh < 8; ++kh) {
    const int k0 = kh * 32 + q4 * 8;
    const bf16x8 ah0 = *(const bf16x8*)&Ahi[n15][k0];
    const bf16x8 ah1 = *(const bf16x8*)&Ahi[16 + n15][k0];
    const bf16x8 al0 = *(const bf16x8*)&Alo[n15][k0];
    const bf16x8 al1 = *(const bf16x8*)&Alo[16 + n15][k0];
    #pragma unroll
    for (int c = 0; c < 2; ++c) {
      const int m = mblk * 128 + wave * 32 + c * 16 + n15;
      const bf16x8 bh = *(const bf16x8*)(z_hi + m * 256 + k0);
      const bf16x8 bl = *(const bf16x8*)(z_lo + m * 256 + k0);
      acc[0][c] = mf(ah0, bh, acc[0][c]);
      acc[1][c] = mf(ah1, bh, acc[1][c]);
      acc[0][c] = mf(ah0, bl, acc[0][c]);
      acc[1][c] = mf(ah1, bl, acc[1][c]);
      acc[0][c] = mf(al0, bh, acc[0][c]);
      acc[1][c] = mf(al1, bh, acc[1][c]);
    }
  }

  #pragma unroll
  for (int r = 0; r < 2; ++r)
    #pragma unroll
    for (int c = 0; c < 2; ++c) {
      const int m  = mblk * 128 + wave * 32 + c * 16 + n15;
      const int ss = m & 127;
      const int td = m >> 7;
      const int cg = c0 + 16 * r + q4 * 4;
      *(f32x4*)(out + ss * (DEC_ * C_) + td * C_ + cg) = acc[r][c];
    }
}

extern "C" void kernel_launch(void* const* d_in, const int* in_sizes, int n_in,
                              void* d_out, int out_size, void* d_ws, size_t ws_size,
                              hipStream_t stream) {
  (void)in_sizes; (void)n_in; (void)out_size;
  const float* x    = (const float*)d_in[0];
  const int*   lens = (const int*)d_in[1];
  // d_in[2] = out_lengths (constant 128), unused
  const float* W_ih = (const float*)d_in[3];
  const float* W_hh = (const float*)d_in[4];
  const float* b_ih = (const float*)d_in[5];
  const float* b_hh = (const float*)d_in[6];
  const float* W1   = (const float*)d_in[7];
  const float* b1   = (const float*)d_in[8];
  const float* W2   = (const float*)d_in[9];
  const float* b2   = (const float*)d_in[10];
  float* out = (float*)d_out;

  char* ws8  = (char*)d_ws;
  char* arrb = ws8;                           // 64 KB wave-flag region (128 B per wave)
  char* ring = ws8 + 65536;                   // RING x 128 KB = 4 MB version ring
  char* decb = ws8 + 65536 + (size_t)RING * 131072;   // 16 MB decoder h log

  const size_t decb_end = 65536 + (size_t)RING * 131072 + 16777216ull;
  const size_t NEED_XS  = decb_end + 2ull * 16777216ull;   // + x hi/lo planes
  const int use_xs = (ws_size >= NEED_XS) ? 1 : 0;

  unsigned short* x_hi; unsigned short* x_lo;
  unsigned short* z_hi; unsigned short* z_lo;
  if (use_xs) {
    x_hi = (unsigned short*)(ws8 + decb_end);
    x_lo = x_hi + (size_t)B_ * T_ * I_;
    z_hi = (unsigned short*)(ws8 + decb_end);        // alias x_hi (dead after rnn5)
    z_lo = z_hi + (size_t)DEC_ * B_ * H_;
  } else {
    x_hi = nullptr; x_lo = nullptr;
    z_hi = (unsigned short*)(ws8 + decb_end);
    z_lo = z_hi + (size_t)DEC_ * B_ * H_;
  }

  (void)hipMemsetAsync(arrb, 0, 65536, stream);              // zero wave flags
  (void)hipMemsetAsync(ring, 0xFF, (size_t)RING * 131072, stream);  // gen-15 sentinel
  if (use_xs) {
    const int n4 = (B_ * T_ * I_) / 4;
    xsplit_k<<<(n4 + 255) / 256, 256, 0, stream>>>(x, x_hi, x_lo, n4);
  }
  rnn5<<<NWG, 256, 0, stream>>>(x, x_hi, x_lo, use_xs, lens,
                                W_ih, W_hh, b_ih, b_hh,
                                arrb, ring, decb);
  mlp1<<<1024, 256, 0, stream>>>(decb, W1, b1, z_hi, z_lo);
  mlp2<<<256, 256, 0, stream>>>(z_hi, z_lo, W2, b2, out);
}